// Round 4
// baseline (268.348 us; speedup 1.0000x reference)
//
#include <hip/hip_runtime.h>

// out[b][i][j] = (j == indices[i]) ? grad[b][i] : 0
// grad (8,4096) f32, indices (4096,) int32, out (8,4096,2048) f32 = 256 MiB.
//
// R8: R6 (fill-identical global sliding window) + NONTEMPORAL stores.
// Evidence so far: three different custom 256 MiB store kernels all ran at
// ~3.3 TB/s while fillBufferAligned runs 6.5 TB/s on the same bytes, and R6
// already matched the fill's address pattern exactly -> the deficit is not
// the access shape. Remaining difference: store cache policy. Theory: our
// compiled global_store_dwordx4 write-allocates in L2 with a fetch/RMW
// round-trip (256 MiB extra fetch ~= +41 us ~= the observed deficit),
// while the fill's stores are recognized as full-line overwrites (its
// FETCH_SIZE ~= 0). Single-variable probe: __builtin_nontemporal_store
// (nt flag, no-allocate/streaming) on the otherwise byte-identical R6.
// If right: fused kernel ~45 us, beats R7's memset+scatter (one dispatch,
// no scatter RMW). If wrong: revert to R7 structure, declare floor.

#define ROWS_PER_B 4096
#define NEWDIM     2048
#define F4_PER_ROW (NEWDIM / 4)        // 512
#define NTHREADS   524288              // 2048 blocks * 256 threads
#define ITERS      32                  // 16.8M f4 slots / 524288

typedef float f32x4 __attribute__((ext_vector_type(4)));

__global__ __launch_bounds__(256)
void ReduceMaxGrad_53833120088407_kernel(const float* __restrict__ grad,
                                         const int*  __restrict__ indices,
                                         float*      __restrict__ out) {
    const int gtid     = blockIdx.x * 256 + threadIdx.x;  // f4-slot in window 0
    const int c4       = gtid & (F4_PER_ROW - 1);         // thread's f4 column (fixed)
    const int row_base = gtid >> 9;                       // block-uniform, 0..1023
    const int c4x4     = c4 << 2;                         // first element owned

    f32x4* o = (f32x4*)out + gtid;

    int   idx = indices[row_base & (ROWS_PER_B - 1)];     // row for iter 0
    float g   = grad[row_base];

#pragma unroll
    for (int i = 0; i < ITERS; ++i) {
        int   nidx = 0;
        float ng   = 0.0f;
        if (i + 1 < ITERS) {                              // prefetch next row
            const int nrow = (i + 1) * 1024 + row_base;   // block-uniform
            nidx = indices[nrow & (ROWS_PER_B - 1)];
            ng   = grad[nrow];
        }
        const int c = idx - c4x4;                         // in [0,3] iff owned
        f32x4 v;
        v.x = (c == 0) ? g : 0.0f;
        v.y = (c == 1) ? g : 0.0f;
        v.z = (c == 2) ? g : 0.0f;
        v.w = (c == 3) ? g : 0.0f;
        __builtin_nontemporal_store(v, &o[(size_t)i * NTHREADS]); // nt: no L2 alloc
        idx = nidx; g = ng;
    }
}

extern "C" void kernel_launch(void* const* d_in, const int* in_sizes, int n_in,
                              void* d_out, int out_size, void* d_ws, size_t ws_size,
                              hipStream_t stream) {
    const float* grad    = (const float*)d_in[0];   // (8, 4096) f32
    const int*   indices = (const int*)d_in[1];     // (4096,) int32
    float*       out     = (float*)d_out;           // (8, 4096, 2048) f32

    ReduceMaxGrad_53833120088407_kernel<<<dim3(2048), dim3(256), 0, stream>>>(
        grad, indices, out);
}

// Round 5
// 229.768 us; speedup vs baseline: 1.1679x; 1.1679x over previous
//
#include <hip/hip_runtime.h>

// out[b][i][j] = (j == indices[i]) ? grad[b][i] : 0
// grad (8,4096) f32, indices (4096,) int32, out (8,4096,2048) f32 = 256 MiB.
//
// R9 = R7 revert (best measured: 228.8 us). memset + scatter.
//
// Session evidence:
//  - R4/R5/R6: three structurally different fused 256 MiB store kernels all
//    ~3.3 TB/s (pattern-independent; scratch / sliding-window / nt theories
//    all refuted, R8 nt stores even regressed to 268 us).
//  - fillBufferAligned (the runtime fill used by hipMemsetAsync) sustains
//    6.5 TB/s on these exact buffers -> let IT write the zeros.
//  - Scatter writes the provable minimum non-zero bytes (32768 dwords).
//
// Cost decomposition (measured): ~167 poison fill (harness, untouchable)
// + ~42 memset (at fill ceiling) + ~6 scatter + ~10 dispatch gaps ~= 229.
// Every controllable term is at its floor; same-stream graph capture
// forbids overlapping memset and scatter (they touch overlapping bytes
// anyway, and ordering is required for correctness).

#define ROWS_PER_B 4096
#define NEWDIM     2048

__global__ __launch_bounds__(512)
void ReduceMaxGrad_53833120088407_scatter(const float* __restrict__ grad,
                                          const int*  __restrict__ indices,
                                          float*      __restrict__ out) {
    const int t = blockIdx.x * 512 + threadIdx.x;     // 0..32767 = b*4096 + i
    const int i = t & (ROWS_PER_B - 1);
    const int idx = indices[i];                       // coalesced across lanes
    const float g = grad[t];                          // coalesced across lanes
    out[(size_t)t * NEWDIM + idx] = g;                // one dword per row
}

extern "C" void kernel_launch(void* const* d_in, const int* in_sizes, int n_in,
                              void* d_out, int out_size, void* d_ws, size_t ws_size,
                              hipStream_t stream) {
    const float* grad    = (const float*)d_in[0];   // (8, 4096) f32
    const int*   indices = (const int*)d_in[1];     // (4096,) int32
    float*       out     = (float*)d_out;           // (8, 4096, 2048) f32

    // Zero the whole output with the runtime's optimized fill (~42 us),
    // then scatter the 32768 non-zeros (~6 us). Same-stream -> ordered.
    hipMemsetAsync(d_out, 0, (size_t)out_size, stream);

    ReduceMaxGrad_53833120088407_scatter<<<dim3(32768 / 512), dim3(512), 0, stream>>>(
        grad, indices, out);
}